// Round 19
// baseline (2054.818 us; speedup 1.0000x reference)
//
#include <hip/hip_runtime.h>
#include <hip/hip_bf16.h>

#define T_STEPS 512
#define BATCH   64
#define IDIM    512
#define HDIM    1024
#define ODIM    512
#define NWG     256           // 4 batch groups x 64 hidden-slice WGs
#define TPB     512           // 8 waves: K-split 8 ways
#define TPB2    256
#define JS      16            // hidden units per WG -> 64 gate cols
#define BGRP    16            // batch rows per group

typedef __bf16 bf16_t;
typedef bf16_t bf16x8 __attribute__((ext_vector_type(8)));
typedef float  f32x4  __attribute__((ext_vector_type(4)));
typedef unsigned short u16;
typedef unsigned int   u32;
typedef u16 u16x8 __attribute__((ext_vector_type(8)));
typedef u32 u32x4 __attribute__((ext_vector_type(4)));

// ws layout (u32): [0,131072) h double buffer of TAGGED u32 cells
// (2 x 64 x 1024; cell = (step_tag<<16)|bf16(h)); then X_bf16.
#define HBUF2_U32 (2 * BATCH * HDIM)     // 131072
#define XB_U16_OFF (2 * HBUF2_U32)

__device__ __forceinline__ float sigmoidf_fast(float x) {
  return 1.0f / (1.0f + __expf(-x));
}
__device__ __forceinline__ float tanhf_fast(float x) {
  float ax = fabsf(x);
  float e  = __expf(-2.0f * ax);
  return copysignf((1.0f - e) / (1.0f + e), x);
}

__global__ void k_init(u32* w) {
  int i = blockIdx.x * blockDim.x + threadIdx.x;
  // zero tagged h buffer: tag 0 == h(0) = 0
  for (int idx = i; idx < HBUF2_U32; idx += gridDim.x * blockDim.x) w[idx] = 0u;
}

__global__ __launch_bounds__(TPB2) void k_xcvt(const float* __restrict__ X,
                                               u16* __restrict__ Xb) {
  size_t i = ((size_t)blockIdx.x * TPB2 + threadIdx.x) * 8;
  f32x4 a = *(const f32x4*)(X + i);
  f32x4 b = *(const f32x4*)(X + i + 4);
  u16x8 o;
  o[0] = __builtin_bit_cast(u16, (bf16_t)a[0]);
  o[1] = __builtin_bit_cast(u16, (bf16_t)a[1]);
  o[2] = __builtin_bit_cast(u16, (bf16_t)a[2]);
  o[3] = __builtin_bit_cast(u16, (bf16_t)a[3]);
  o[4] = __builtin_bit_cast(u16, (bf16_t)b[0]);
  o[5] = __builtin_bit_cast(u16, (bf16_t)b[1]);
  o[6] = __builtin_bit_cast(u16, (bf16_t)b[2]);
  o[7] = __builtin_bit_cast(u16, (bf16_t)b[3]);
  *(u16x8*)(Xb + i) = o;
}

__device__ __forceinline__ bf16x8 cvt8(const float* src) {
  f32x4 u = *(const f32x4*)(src);
  f32x4 v = *(const f32x4*)(src + 4);
  bf16x8 t;
  t[0] = (bf16_t)u[0]; t[1] = (bf16_t)u[1]; t[2] = (bf16_t)u[2]; t[3] = (bf16_t)u[3];
  t[4] = (bf16_t)v[0]; t[5] = (bf16_t)v[1]; t[6] = (bf16_t)v[2]; t[7] = (bf16_t)v[3];
  return t;
}

// acc[ct] += A * wf[i*4+ct]   (ct = gate, i = k-tile slot of this wave)
#define MFA(CT, AF, WI) \
  acc[CT] = __builtin_amdgcn_mfma_f32_16x16x32_bf16((AF), wf[(WI)*4+(CT)], acc[CT], 0, 0, 0)

// tagged-cell poll load, LLC-coherent
#define PLD(DST, PTR, OFFB) \
  asm volatile("global_load_dwordx4 %0, %1, off offset:" OFFB " sc0 sc1" : "=v"(DST) : "v"(PTR))

#define GWS 20   // gw inner stride (floats): 16B-aligned; reads 2-way

// extract 8 bf16 from two tagged u32x4 (low halves), pack to MFMA A-frag
__device__ __forceinline__ bf16x8 pack8(u32x4 a, u32x4 b) {
  u32x4 r;
  r[0] = (a[0] & 0xFFFFu) | (a[1] << 16);
  r[1] = (a[2] & 0xFFFFu) | (a[3] << 16);
  r[2] = (b[0] & 0xFFFFu) | (b[1] << 16);
  r[3] = (b[2] & 0xFFFFu) | (b[3] << 16);
  return __builtin_bit_cast(bf16x8, r);
}
__device__ __forceinline__ int tags_ok(u32x4 a, u32x4 b, u32 tag) {
  return (a[0] >> 16) == tag && (a[1] >> 16) == tag &&
         (a[2] >> 16) == tag && (a[3] >> 16) == tag &&
         (b[0] >> 16) == tag && (b[1] >> 16) == tag &&
         (b[2] >> 16) == tag && (b[3] >> 16) == tag;
}

__global__ __launch_bounds__(TPB, 2) void k_lstm(
    const u16* __restrict__ Xb, const float* __restrict__ Wih,
    const float* __restrict__ Whh, const float* __restrict__ bih,
    const float* __restrict__ bhh, u32* __restrict__ hbuf) {
  __shared__ float gw[8][64][GWS];   // 40 KB cross-wave partials [wave][gatecol][batch16+pad]

  const int wg   = blockIdx.x;
  const int grp  = wg >> 6;          // batch group 0..3 (rows grp*16 .. +16)
  const int widx = wg & 63;          // hidden-slice index (units widx*16 .. +16)
  const int tid  = threadIdx.x;
  const int w    = tid >> 6;         // wave = k-split slice
  const int lane = tid & 63;
  const int am   = lane & 15;
  const int kg   = lane >> 4;

  // ---- time-invariant weights in registers: wave w owns k-tiles w+8i, i=0..5 ----
  bf16x8 wf[24];
  #pragma unroll
  for (int ct = 0; ct < 4; ++ct) {
    int gr = ct * HDIM + widx * JS + am;   // gate col ct*16+am of this WG
    #pragma unroll
    for (int i = 0; i < 2; ++i)
      wf[i * 4 + ct] = cvt8(Wih + (size_t)gr * IDIM + (w + 8 * i) * 32 + kg * 8);
    #pragma unroll
    for (int i = 2; i < 6; ++i)
      wf[i * 4 + ct] = cvt8(Whh + (size_t)gr * HDIM + (w + 8 * i) * 32 + kg * 8 - IDIM);
  }

  // epilogue: one cell per thread for tid<256: local batch row ebl, unit ej
  const int ebl = tid >> 4;          // 0..15 (for tid < 256)
  const int ej  = tid & 15;          // 0..15
  float bias[4];
  #pragma unroll
  for (int g = 0; g < 4; ++g) {
    int r = g * HDIM + widx * JS + ej;
    bias[g] = bih[r] + bhh[r];
  }
  float c = 0.f;

  f32x4 acc[4];

  // X-part phase: acc += X(tt) @ Wih-slice (L2-warm, never invalidated)
  auto xphase = [&](int tt) {
    const u16* xb = Xb + ((size_t)tt * BATCH + grp * BGRP + am) * IDIM + w * 32 + kg * 8;
    #pragma unroll
    for (int i = 0; i < 2; ++i) {
      bf16x8 xa = *(const bf16x8*)(xb + i * 256);
      MFA(0, xa, i); MFA(1, xa, i); MFA(2, xa, i); MFA(3, xa, i);
    }
  };

  // prologue: X(0) partials (h(0)=0 with tag 0 from k_init)
  #pragma unroll
  for (int ct = 0; ct < 4; ++ct) acc[ct] = (f32x4){0.f, 0.f, 0.f, 0.f};
  xphase(0);

  int cur = 0;
  for (int t = 0; t < T_STEPS; ++t) {
    // ---- poll-load tagged h(cur): detection == data arrival (no flags) ----
    // wave w needs cells w*32 + i2*256 + kg*8 .. +8 for chunks i2=0..3
    const u32* hb = hbuf + (size_t)cur * BATCH * HDIM
                  + (size_t)(grp * BGRP + am) * HDIM + w * 32 + kg * 8;
    u32x4 d0a, d0b, d1a, d1b, d2a, d2b, d3a, d3b;
    {
      const u32 tag = (u32)t;
      int ok0 = 0, ok1 = 0, ok2 = 0, ok3 = 0;
      while (true) {
        if (!ok0) { PLD(d0a, hb, "0");    PLD(d0b, hb, "16");   }
        if (!ok1) { PLD(d1a, hb, "1024"); PLD(d1b, hb, "1040"); }
        if (!ok2) { PLD(d2a, hb, "2048"); PLD(d2b, hb, "2064"); }
        if (!ok3) { PLD(d3a, hb, "3072"); PLD(d3b, hb, "3088"); }
        asm volatile("s_waitcnt vmcnt(0)" ::: "memory");
        if (!ok0) ok0 = __all(tags_ok(d0a, d0b, tag));
        if (!ok1) ok1 = __all(tags_ok(d1a, d1b, tag));
        if (!ok2) ok2 = __all(tags_ok(d2a, d2b, tag));
        if (!ok3) ok3 = __all(tags_ok(d3a, d3b, tag));
        if (ok0 & ok1 & ok2 & ok3) break;
        __builtin_amdgcn_s_sleep(1);
      }
    }
    __builtin_amdgcn_sched_barrier(0);

    // extract + h MFMAs (chunk i2 -> k-slot 2+i2)
    {
      bf16x8 h0 = pack8(d0a, d0b);
      bf16x8 h1 = pack8(d1a, d1b);
      MFA(0, h0, 2); MFA(1, h0, 2); MFA(2, h0, 2); MFA(3, h0, 2);
      MFA(0, h1, 3); MFA(1, h1, 3); MFA(2, h1, 3); MFA(3, h1, 3);
      bf16x8 h2 = pack8(d2a, d2b);
      bf16x8 h3 = pack8(d3a, d3b);
      MFA(0, h2, 4); MFA(1, h2, 4); MFA(2, h2, 4); MFA(3, h2, 4);
      MFA(0, h3, 5); MFA(1, h3, 5); MFA(2, h3, 5); MFA(3, h3, 5);
    }

    // partial sums -> LDS: [gatecol = ct*16+am][batch = kg*4]
    #pragma unroll
    for (int ct = 0; ct < 4; ++ct)
      *(f32x4*)&gw[w][ct * 16 + am][kg * 4] = acc[ct];
    __syncthreads();   // #1: partials visible

    // reduce over 8 waves + activations; one cell per thread (tid < 256)
    if (tid < 256) {
      float s0 = 0.f, s1 = 0.f, s2 = 0.f, s3 = 0.f;
      #pragma unroll
      for (int ww = 0; ww < 8; ++ww) {
        s0 += gw[ww][ej][ebl];
        s1 += gw[ww][16 + ej][ebl];
        s2 += gw[ww][32 + ej][ebl];
        s3 += gw[ww][48 + ej][ebl];
      }
      float pi = s0 + bias[0], pf = s1 + bias[1];
      float pg = s2 + bias[2], po = s3 + bias[3];
      c = sigmoidf_fast(pf) * c + sigmoidf_fast(pi) * tanhf_fast(pg);
      float h = sigmoidf_fast(po) * tanhf_fast(c);
      u16 hu = __builtin_bit_cast(u16, (bf16_t)h);
      u32 word = ((u32)(t + 1) << 16) | (u32)hu;   // tagged cell: atomic dword
      u32* hp = hbuf + (size_t)(cur ^ 1) * BATCH * HDIM
              + (size_t)(grp * BGRP + ebl) * HDIM + widx * JS + ej;
      asm volatile("global_store_dword %0, %1, off sc0 sc1"   // write-through to LLC
                   :: "v"(hp), "v"(word) : "memory");
    }
    __syncthreads();   // #2: gw/LDS anti-dependence (r13-proven lockstep)

    if (t != T_STEPS - 1) {
      // next step's X partials (overlaps producers' store latency chip-wide)
      #pragma unroll
      for (int ct = 0; ct < 4; ++ct) acc[ct] = (f32x4){0.f, 0.f, 0.f, 0.f};
      xphase(t + 1);
    }
    cur ^= 1;
  }
}

__global__ __launch_bounds__(TPB2) void k_out(
    const u32* __restrict__ hfin, const float* __restrict__ Who,
    const float* __restrict__ bho, float* __restrict__ out) {
  int gid = blockIdx.x * TPB2 + threadIdx.x;  // 0..32767
  int b   = gid & 63;
  int oc  = gid >> 6;
  const u32* hrow = hfin + b * HDIM;
  const float* wrow = Who + oc * HDIM;
  float s = bho[oc];
  for (int k = 0; k < HDIM; k += 4) {
    u32x4 hv = *(const u32x4*)(hrow + k);
    f32x4 wv = *(const f32x4*)(wrow + k);
    #pragma unroll
    for (int q = 0; q < 4; ++q) {
      float hf = (float)__builtin_bit_cast(bf16_t, (u16)(hv[q] & 0xFFFFu));
      s += hf * wv[q];
    }
  }
  out[b * ODIM + oc] = s;
}

extern "C" void kernel_launch(void* const* d_in, const int* in_sizes, int n_in,
                              void* d_out, int out_size, void* d_ws, size_t ws_size,
                              hipStream_t stream) {
  const float* X   = (const float*)d_in[0];
  const float* Wih = (const float*)d_in[1];
  const float* Whh = (const float*)d_in[2];
  const float* bih = (const float*)d_in[3];
  const float* bhh = (const float*)d_in[4];
  const float* Who = (const float*)d_in[5];
  const float* bho = (const float*)d_in[6];

  u32* hbuf = (u32*)d_ws;
  u16* Xb   = (u16*)d_ws + XB_U16_OFF;

  k_init<<<64, TPB2, 0, stream>>>(hbuf);
  k_xcvt<<<(T_STEPS * BATCH * IDIM) / (TPB2 * 8), TPB2, 0, stream>>>(X, Xb);
  k_lstm<<<NWG, TPB, 0, stream>>>(Xb, Wih, Whh, bih, bhh, hbuf);
  // final h(512) lives in slot 0 (cur toggles 512 times from 0)
  k_out<<<(BATCH * ODIM) / TPB2, TPB2, 0, stream>>>(hbuf, Who, bho, (float*)d_out);
}

// Round 20
// 1451.079 us; speedup vs baseline: 1.4161x; 1.4161x over previous
//
#include <hip/hip_runtime.h>
#include <hip/hip_bf16.h>

#define T_STEPS 512
#define BATCH   64
#define IDIM    512
#define HDIM    1024
#define ODIM    512
#define NWG     256           // 4 batch groups x 64 hidden-slice WGs
#define TPB     512           // 8 waves: K-split 8 ways
#define TPB2    256
#define JS      16            // hidden units per WG -> 64 gate cols
#define BGRP    16            // batch rows per group

typedef __bf16 bf16_t;
typedef bf16_t bf16x8 __attribute__((ext_vector_type(8)));
typedef float  f32x4  __attribute__((ext_vector_type(4)));
typedef unsigned short u16;
typedef unsigned int   u32;
typedef u16 u16x8 __attribute__((ext_vector_type(8)));

// ws layout (u32): [0,65536) h double buffer; [65536,73728) 256 WG-flags @128B; then X_bf16
#define HBUF_U32 65536
#define FLG_U32  8192
#define XB_U16_OFF (2 * (HBUF_U32 + FLG_U32))

__device__ __forceinline__ float sigmoidf_fast(float x) {
  return 1.0f / (1.0f + __expf(-x));
}
__device__ __forceinline__ float tanhf_fast(float x) {
  float ax = fabsf(x);
  float e  = __expf(-2.0f * ax);
  return copysignf((1.0f - e) / (1.0f + e), x);
}

__global__ void k_init(u32* w) {
  int i = blockIdx.x * blockDim.x + threadIdx.x;
  for (int idx = i; idx < HBUF_U32 + FLG_U32; idx += gridDim.x * blockDim.x) w[idx] = 0u;
}

__global__ __launch_bounds__(TPB2) void k_xcvt(const float* __restrict__ X,
                                               u16* __restrict__ Xb) {
  size_t i = ((size_t)blockIdx.x * TPB2 + threadIdx.x) * 8;
  f32x4 a = *(const f32x4*)(X + i);
  f32x4 b = *(const f32x4*)(X + i + 4);
  u16x8 o;
  o[0] = __builtin_bit_cast(u16, (bf16_t)a[0]);
  o[1] = __builtin_bit_cast(u16, (bf16_t)a[1]);
  o[2] = __builtin_bit_cast(u16, (bf16_t)a[2]);
  o[3] = __builtin_bit_cast(u16, (bf16_t)a[3]);
  o[4] = __builtin_bit_cast(u16, (bf16_t)b[0]);
  o[5] = __builtin_bit_cast(u16, (bf16_t)b[1]);
  o[6] = __builtin_bit_cast(u16, (bf16_t)b[2]);
  o[7] = __builtin_bit_cast(u16, (bf16_t)b[3]);
  *(u16x8*)(Xb + i) = o;
}

__device__ __forceinline__ bf16x8 cvt8(const float* src) {
  f32x4 u = *(const f32x4*)src;
  f32x4 v = *(const f32x4*)(src + 4);
  bf16x8 t;
  t[0] = (bf16_t)u[0]; t[1] = (bf16_t)u[1]; t[2] = (bf16_t)u[2]; t[3] = (bf16_t)u[3];
  t[4] = (bf16_t)v[0]; t[5] = (bf16_t)v[1]; t[6] = (bf16_t)v[2]; t[7] = (bf16_t)v[3];
  return t;
}

// acc[ct] += A * wf[i*4+ct]   (ct = gate, i = k-tile slot of this wave)
#define MFA(CT, AF, WI) \
  acc[CT] = __builtin_amdgcn_mfma_f32_16x16x32_bf16((AF), wf[(WI)*4+(CT)], acc[CT], 0, 0, 0)

// pinned h load, LLC-coherent (sc0 sc1): reads at the coherence point, immune to
// in-flight peer-L2 invalidations (r12's absmax wobble). Perf-neutral: r6 === r8.
#define GLDH(DST, PTR, OFFB) \
  asm volatile("global_load_dwordx4 %0, %1, off offset:" OFFB " sc0 sc1" : "=v"(DST) : "v"(PTR))

#define GWS 20   // gw inner stride (floats): 16B-aligned; reads ~2-way

__global__ __launch_bounds__(TPB, 2) void k_lstm(
    const u16* __restrict__ Xb, const float* __restrict__ Wih,
    const float* __restrict__ Whh, const float* __restrict__ bih,
    const float* __restrict__ bhh, u16* __restrict__ hbuf,
    u32* __restrict__ flg) {
  __shared__ float gw[8][64][GWS];   // 40 KB cross-wave partials [wave][gatecol][batch16+pad]

  const int wg   = blockIdx.x;
  const int grp  = wg >> 6;          // batch group 0..3 (rows grp*16 .. +16)
  const int widx = wg & 63;          // hidden-slice index (units widx*16 .. +16)
  const int tid  = threadIdx.x;
  const int w    = tid >> 6;         // wave = k-split slice
  const int lane = tid & 63;
  const int am   = lane & 15;
  const int kg   = lane >> 4;

  // ---- time-invariant weights in registers: wave w owns k-tiles w+8i, i=0..5 ----
  bf16x8 wf[24];
  #pragma unroll
  for (int ct = 0; ct < 4; ++ct) {
    int gr = ct * HDIM + widx * JS + am;   // gate col ct*16+am of this WG
    #pragma unroll
    for (int i = 0; i < 2; ++i)
      wf[i * 4 + ct] = cvt8(Wih + (size_t)gr * IDIM + (w + 8 * i) * 32 + kg * 8);
    #pragma unroll
    for (int i = 2; i < 6; ++i)
      wf[i * 4 + ct] = cvt8(Whh + (size_t)gr * HDIM + (w + 8 * i) * 32 + kg * 8 - IDIM);
  }

  // this wave's 8 h-producer WGs: widx_p = 2w + (j&1) + 16*(j>>1); lane j<8 polls one
  u32* myflag = (lane < 8)
    ? flg + ((size_t)(grp * 64 + 2 * w + (lane & 1) + 16 * (lane >> 1)) * 32)
    : flg;
  u32* ownflag = flg + ((size_t)(grp * 64 + widx) * 32);

  // epilogue: one cell per thread for tid<256: local batch row ebl, unit ej
  const int ebl = tid >> 4;          // 0..15 (for tid < 256)
  const int ej  = tid & 15;          // 0..15
  float bias[4];
  #pragma unroll
  for (int g = 0; g < 4; ++g) {
    int r = g * HDIM + widx * JS + ej;
    bias[g] = bih[r] + bhh[r];
  }
  float c = 0.f;

  f32x4 acc[4];

  // X-part phase: acc += X(tt) @ Wih-slice (L2-warm, never invalidated)
  auto xphase = [&](int tt) {
    const u16* xb = Xb + ((size_t)tt * BATCH + grp * BGRP + am) * IDIM + w * 32 + kg * 8;
    #pragma unroll
    for (int i = 0; i < 2; ++i) {
      bf16x8 xa = *(const bf16x8*)(xb + i * 256);
      MFA(0, xa, i); MFA(1, xa, i); MFA(2, xa, i); MFA(3, xa, i);
    }
  };

  // prologue: X(0) partials (h(0)=0 from k_init; flags start 0, no wait at t=0)
  #pragma unroll
  for (int ct = 0; ct < 4; ++ct) acc[ct] = (f32x4){0.f, 0.f, 0.f, 0.f};
  xphase(0);

  int cur = 0;
  for (int t = 0; t < T_STEPS; ++t) {
    // ---- 4 pinned h loads (LLC-coherent), counted waits ----
    bf16x8 h0, h1, h2, h3;
    const u16* hb0 = hbuf + (size_t)cur * BATCH * HDIM
                   + (size_t)(grp * BGRP + am) * HDIM + w * 32 + kg * 8;
    GLDH(h0, hb0, "0");
    GLDH(h1, hb0, "512");
    GLDH(h2, hb0, "1024");
    GLDH(h3, hb0, "1536");
    __builtin_amdgcn_sched_barrier(0);

    asm volatile("s_waitcnt vmcnt(2)" ::: "memory");   // h0, h1 landed
    __builtin_amdgcn_sched_barrier(0);
    MFA(0, h0, 2); MFA(1, h0, 2); MFA(2, h0, 2); MFA(3, h0, 2);
    MFA(0, h1, 3); MFA(1, h1, 3); MFA(2, h1, 3); MFA(3, h1, 3);

    asm volatile("s_waitcnt vmcnt(0)" ::: "memory");   // h2, h3 landed
    __builtin_amdgcn_sched_barrier(0);
    MFA(0, h2, 4); MFA(1, h2, 4); MFA(2, h2, 4); MFA(3, h2, 4);
    MFA(0, h3, 5); MFA(1, h3, 5); MFA(2, h3, 5); MFA(3, h3, 5);

    // partial sums -> LDS: [gatecol = ct*16+am][batch = kg*4]
    #pragma unroll
    for (int ct = 0; ct < 4; ++ct)
      *(f32x4*)&gw[w][ct * 16 + am][kg * 4] = acc[ct];
    __syncthreads();   // #1: partials visible

    // reduce over 8 waves + activations; one cell per thread (tid < 256)
    if (tid < 256) {
      float s0 = 0.f, s1 = 0.f, s2 = 0.f, s3 = 0.f;
      #pragma unroll
      for (int ww = 0; ww < 8; ++ww) {
        s0 += gw[ww][ej][ebl];
        s1 += gw[ww][16 + ej][ebl];
        s2 += gw[ww][32 + ej][ebl];
        s3 += gw[ww][48 + ej][ebl];
      }
      float pi = s0 + bias[0], pf = s1 + bias[1];
      float pg = s2 + bias[2], po = s3 + bias[3];
      c = sigmoidf_fast(pf) * c + sigmoidf_fast(pi) * tanhf_fast(pg);
      float h = sigmoidf_fast(po) * tanhf_fast(c);
      u16 hu = __builtin_bit_cast(u16, (bf16_t)h);
      u16* hp = hbuf + (size_t)(cur ^ 1) * BATCH * HDIM
              + (size_t)(grp * BGRP + ebl) * HDIM + widx * JS + ej;
      asm volatile("global_store_short %0, %1, off sc0 sc1"   // write-through to LLC
                   :: "v"(hp), "v"((u32)hu) : "memory");
    }
    __syncthreads();   // #2: all 8 waves' stores drained -> slice complete at LLC

    if (t != T_STEPS - 1) {
      // publish: single plain write-through store (no atomic RMW contention)
      if (tid == 0) {
        u32 fv = (u32)(t + 1);
        asm volatile("global_store_dword %0, %1, off sc0 sc1"
                     :: "v"(ownflag), "v"(fv) : "memory");
      }

      // overlap wait with next step's X-part MFMAs
      #pragma unroll
      for (int ct = 0; ct < 4; ++ct) acc[ct] = (f32x4){0.f, 0.f, 0.f, 0.f};
      xphase(t + 1);

      // per-wave dataflow wait: 8 producer-WG flags (lanes 0-7, agent scope)
      {
        const u32 tgt = (u32)(t + 1);
        while (true) {
          u32 v = (lane < 8)
            ? __hip_atomic_load(myflag, __ATOMIC_RELAXED, __HIP_MEMORY_SCOPE_AGENT)
            : tgt;
          if (__all((int)(v >= tgt))) break;
          __builtin_amdgcn_s_sleep(1);
        }
      }
      __builtin_amdgcn_sched_barrier(0);
    }
    cur ^= 1;
  }
}

__global__ __launch_bounds__(TPB2) void k_out(
    const u16* __restrict__ hfin, const float* __restrict__ Who,
    const float* __restrict__ bho, float* __restrict__ out) {
  int gid = blockIdx.x * TPB2 + threadIdx.x;  // 0..32767
  int b   = gid & 63;
  int oc  = gid >> 6;
  const u16* hrow = hfin + b * HDIM;
  const float* wrow = Who + oc * HDIM;
  float s = bho[oc];
  for (int k = 0; k < HDIM; k += 8) {
    bf16x8 hv = *(const bf16x8*)(hrow + k);
    f32x4 w0 = *(const f32x4*)(wrow + k);
    f32x4 w1 = *(const f32x4*)(wrow + k + 4);
    s += (float)hv[0] * w0[0] + (float)hv[1] * w0[1] + (float)hv[2] * w0[2] + (float)hv[3] * w0[3]
       + (float)hv[4] * w1[0] + (float)hv[5] * w1[1] + (float)hv[6] * w1[2] + (float)hv[7] * w1[3];
  }
  out[b * ODIM + oc] = s;
}

extern "C" void kernel_launch(void* const* d_in, const int* in_sizes, int n_in,
                              void* d_out, int out_size, void* d_ws, size_t ws_size,
                              hipStream_t stream) {
  const float* X   = (const float*)d_in[0];
  const float* Wih = (const float*)d_in[1];
  const float* Whh = (const float*)d_in[2];
  const float* bih = (const float*)d_in[3];
  const float* bhh = (const float*)d_in[4];
  const float* Who = (const float*)d_in[5];
  const float* bho = (const float*)d_in[6];

  u32* ws32 = (u32*)d_ws;
  u16* hbuf = (u16*)d_ws;
  u32* flg  = ws32 + HBUF_U32;
  u16* Xb   = (u16*)d_ws + XB_U16_OFF;

  k_init<<<64, TPB2, 0, stream>>>(ws32);
  k_xcvt<<<(T_STEPS * BATCH * IDIM) / (TPB2 * 8), TPB2, 0, stream>>>(X, Xb);
  k_lstm<<<NWG, TPB, 0, stream>>>(Xb, Wih, Whh, bih, bhh, hbuf, flg);
  k_out<<<(BATCH * ODIM) / TPB2, TPB2, 0, stream>>>(hbuf, Who, bho, (float*)d_out);
}